// Round 1
// baseline (220.499 us; speedup 1.0000x reference)
//
#include <hip/hip_runtime.h>

// InteractionLayer (SchNet-style) fused kernel for MI355X.
// Shapes (hardcoded to the reference setup): B=4, N=256, NF=H=128, K=300.
// d_in: 0=node_feat[4,256,128] 1=pos[4,256,3] 2=valid[4,256]
//       3=W_f1[300,128] 4=W_f2[128,128] 5=W_a1[128,128] 6=W_a2[128,128] 7=W_a3[128,128]
// d_out: [4,256,128] float32.  d_ws: needs 76,800 B (f16-packed W_f1).
//
// Key algorithmic point: rbf[k]=exp(-10*(d-0.1k)^2) is <1e-9 outside a
// 32-wide window of k around 10*d, so the K=300 contraction is truncated to 32
// (error ~1e-9 << 8.7e-2 threshold). j's are sorted by window start per block
// (stable -> deterministic) for W_f1 L1 locality; only sum_j is consumed so
// the permutation never needs undoing.

typedef _Float16 h2 __attribute__((ext_vector_type(2)));

__device__ __forceinline__ float fdot2f(unsigned int a, unsigned int b, float c) {
#if __has_builtin(__builtin_amdgcn_fdot2)
  return __builtin_amdgcn_fdot2(__builtin_bit_cast(h2, a),
                                __builtin_bit_cast(h2, b), c, false);
#else
  h2 ha = __builtin_bit_cast(h2, a), hb = __builtin_bit_cast(h2, b);
  return c + (float)ha.x * (float)hb.x + (float)ha.y * (float)hb.y;
#endif
}

// ssp(x) = softplus(x) + log(0.5), stable form
__device__ __forceinline__ float sspf(float x) {
  return fmaxf(x, 0.f) + __logf(1.f + __expf(-fabsf(x))) - 0.693147180559945f;
}

// Pack W_f1 [300,128] f32 -> [150,128] u32 of (f16 k, f16 k+1) pairs.
__global__ void prep_w1_kernel(const float* __restrict__ W1,
                               unsigned int* __restrict__ W1p) {
  int gid = blockIdx.x * 256 + threadIdx.x;
  if (gid < 150 * 128) {
    int kp = gid >> 7, h = gid & 127;
    h2 p;
    p.x = (_Float16)W1[(2 * kp) * 128 + h];
    p.y = (_Float16)W1[(2 * kp + 1) * 128 + h];
    W1p[gid] = __builtin_bit_cast(unsigned int, p);
  }
}

__global__ __launch_bounds__(256, 2) void interaction_kernel(
    const float* __restrict__ nodef, const float* __restrict__ pos,
    const float* __restrict__ valid, const unsigned int* __restrict__ W1p,
    const float* __restrict__ W2, const float* __restrict__ Wa1,
    const float* __restrict__ Wa2, const float* __restrict__ Wa3,
    float* __restrict__ out) {
  // 61,184 B static LDS -> 2 blocks/CU
  __shared__ __align__(16) _Float16 W2t[128 * 136];  // W_f2^T [h][k], pad 136
  __shared__ __align__(16) _Float16 ys[64 * 136];    // y chunk [j][k], pad 136
  __shared__ __align__(16) _Float16 rbfw[64 * 32];   // rbf window [j][32]
  __shared__ float d_lds[256];
  __shared__ int kstf[256];
  __shared__ unsigned short jord[256];
  __shared__ int kst_ord[64];
  __shared__ float xrow[128], h1row[128], hhrow[128], a2row[128];

  const int t = threadIdx.x;
  const int bid = blockIdx.x;  // = b*256 + i
  const int b = bid >> 8;

  // ---- phase 0: stage x-row, distances + windows, W_f2^T ----
  if (t < 128) xrow[t] = nodef[bid * 128 + t];
  {
    const float qx = pos[bid * 3 + 0], qy = pos[bid * 3 + 1], qz = pos[bid * 3 + 2];
    const float px = pos[(b * 256 + t) * 3 + 0];
    const float py = pos[(b * 256 + t) * 3 + 1];
    const float pz = pos[(b * 256 + t) * 3 + 2];
    const float dx = px - qx, dy = py - qy, dz = pz - qz;
    const float dd = sqrtf(dx * dx + dy * dy + dz * dz);
    d_lds[t] = dd;
    int k0 = __float2int_rn(dd * 10.f);
    int kst = (k0 & ~1) - 16;  // even start so k-pairs align with W1p packing
    kst = kst < 0 ? 0 : kst;
    kst = kst > 268 ? 268 : kst;
    kstf[t] = kst;
  }
  for (int e = t; e < 128 * 128; e += 256) {
    int k = e >> 7, hh = e & 127;
    W2t[hh * 136 + k] = (_Float16)W2[e];
  }
  __syncthreads();

  // ---- stable rank-sort of j by window start (deterministic) ----
  {
    const int key = kstf[t];
    int rank = 0;
    for (int j2 = 0; j2 < 256; ++j2) {
      int k2 = kstf[j2];
      rank += (k2 < key || (k2 == key && j2 < t)) ? 1 : 0;
    }
    jord[rank] = (unsigned short)t;
  }
  // ---- h1 = x @ W_a1 ----
  if (t < 128) {
    float acc = 0.f;
#pragma unroll 8
    for (int k = 0; k < 128; ++k) acc += xrow[k] * Wa1[k * 128 + t];
    h1row[t] = acc;
  }
  __syncthreads();

  float sumv[8];
#pragma unroll
  for (int r = 0; r < 8; ++r) sumv[r] = 0.f;
  const int hg = t >> 4, jq = t & 15;   // GEMV2 mapping (jq fast -> hg broadcast)
  const int jg = t >> 7, hc = t & 127;  // GEMV1 mapping

  // ---- main loop: 4 chunks of 64 sorted j's ----
  for (int cc = 0; cc < 4; ++cc) {
    // phase A: rbf windows (f16) for this chunk
    for (int v = t; v < 64 * 32; v += 256) {
      const int idx = v >> 5, kq = v & 31;
      const int j = jord[cc * 64 + idx];
      const float dd = d_lds[j];
      const int kst = kstf[j];
      if (kq == 0) kst_ord[idx] = kst;
      const float df = dd - (float)(kst + kq) * 0.1f;
      rbfw[v] = (_Float16)__expf(-10.f * df * df);
    }
    __syncthreads();

    // phase B: y[j][h] = ssp(sum_k rbf*W1) over the 32-wide window (dot2)
    for (int ii = 0; ii < 32; ++ii) {
      const int idx = jg * 32 + ii;
      const int kst = kst_ord[idx];
      const unsigned int* wp = W1p + ((kst >> 1) * 128 + hc);
      const unsigned int* rp = (const unsigned int*)(rbfw + idx * 32);
      float acc = 0.f;
#pragma unroll
      for (int m = 0; m < 16; ++m) acc = fdot2f(rp[m], wp[m * 128], acc);
      ys[idx * 136 + hc] = (_Float16)sspf(acc);
    }
    __syncthreads();

    // phase C: z = ssp(y @ W_f2); accumulate sum_j. Tile 4j x 8h per thread.
    float acc2[4][8];
#pragma unroll
    for (int ji = 0; ji < 4; ++ji)
#pragma unroll
      for (int r = 0; r < 8; ++r) acc2[ji][r] = 0.f;
#pragma unroll 4
    for (int ko = 0; ko < 16; ++ko) {
      uint4 yv[4], wv[8];
#pragma unroll
      for (int ji = 0; ji < 4; ++ji)
        yv[ji] = *(const uint4*)(ys + (jq + 16 * ji) * 136 + 8 * ko);
#pragma unroll
      for (int r = 0; r < 8; ++r)
        wv[r] = *(const uint4*)(W2t + (8 * hg + r) * 136 + 8 * ko);
#pragma unroll
      for (int ji = 0; ji < 4; ++ji)
#pragma unroll
        for (int r = 0; r < 8; ++r) {
          float a = acc2[ji][r];
          a = fdot2f(yv[ji].x, wv[r].x, a);
          a = fdot2f(yv[ji].y, wv[r].y, a);
          a = fdot2f(yv[ji].z, wv[r].z, a);
          a = fdot2f(yv[ji].w, wv[r].w, a);
          acc2[ji][r] = a;
        }
    }
#pragma unroll
    for (int ji = 0; ji < 4; ++ji)
#pragma unroll
      for (int r = 0; r < 8; ++r) sumv[r] += sspf(acc2[ji][r]);
    __syncthreads();
  }

  // ---- reduce sum_j across the 16 jq groups (reuse ys as f32 scratch) ----
  {
    float* red = (float*)ys;
#pragma unroll
    for (int r = 0; r < 8; ++r) red[jq * 128 + 8 * hg + r] = sumv[r];
  }
  __syncthreads();
  if (t < 128) {
    const float* red = (const float*)ys;
    float s = 0.f;
#pragma unroll
    for (int q = 0; q < 16; ++q) s += red[q * 128 + t];
    hhrow[t] = h1row[t] * s;  // CFConv: h * sum_j filt
  }
  __syncthreads();
  if (t < 128) {
    float acc = 0.f;
#pragma unroll 8
    for (int k = 0; k < 128; ++k) acc += hhrow[k] * Wa2[k * 128 + t];
    a2row[t] = sspf(acc);
  }
  __syncthreads();
  if (t < 128) {
    float acc = 0.f;
#pragma unroll 8
    for (int k = 0; k < 128; ++k) acc += a2row[k] * Wa3[k * 128 + t];
    out[bid * 128 + t] = xrow[t] + acc * valid[bid];
  }
}

extern "C" void kernel_launch(void* const* d_in, const int* in_sizes, int n_in,
                              void* d_out, int out_size, void* d_ws, size_t ws_size,
                              hipStream_t stream) {
  const float* nodef = (const float*)d_in[0];
  const float* pos   = (const float*)d_in[1];
  const float* valid = (const float*)d_in[2];
  const float* W1    = (const float*)d_in[3];
  const float* W2    = (const float*)d_in[4];
  const float* Wa1   = (const float*)d_in[5];
  const float* Wa2   = (const float*)d_in[6];
  const float* Wa3   = (const float*)d_in[7];
  float* outp = (float*)d_out;
  unsigned int* W1p = (unsigned int*)d_ws;  // 150*128*4 = 76,800 B

  prep_w1_kernel<<<75, 256, 0, stream>>>(W1, W1p);
  interaction_kernel<<<1024, 256, 0, stream>>>(nodef, pos, valid, W1p, W2,
                                               Wa1, Wa2, Wa3, outp);
}

// Round 2
// 112.876 us; speedup vs baseline: 1.9535x; 1.9535x over previous
//
#include <hip/hip_runtime.h>

// InteractionLayer (SchNet-style) — MFMA f16 version for MI355X (gfx950).
// Shapes hardcoded: B=4, N=256, NF=H=128, K=300 filters, gamma=10, spacing=0.1.
// Block = one (b,i) row: 1024 blocks x 512 threads (8 waves: jg 0..3 x hgrp 0..1).
// GEMM1: rbf[64j x 320k] @ W1[320x128] via 16x16x32 f16 MFMA; rbf A-frags are
//   computed in registers (exp==0 outside window); K-steps restricted per sorted
//   16-row group (windows of sorted j's overlap -> ~2-3 of 10 K-steps).
// GEMM2: ssp(y)[64x128] @ W2[128x128] dense MFMA.
// W1/W2 pre-packed into per-lane B-fragment layout in d_ws by prep kernel.
//
// MFMA 16x16x32 layouts used (gfx950):
//   A: lane l elem j -> A[l&15][(l>>4)*8 + j]
//   B: lane l elem j -> B[(l>>4)*8 + j][l&15]
//   D: lane l reg  r -> D[(l>>4)*4 + r][l&15]

typedef _Float16 f16x8 __attribute__((ext_vector_type(8)));
typedef float f32x4 __attribute__((ext_vector_type(4)));

// ssp(x) = softplus(x) + log(0.5), stable form
__device__ __forceinline__ float sspf(float x) {
  return fmaxf(x, 0.f) + __logf(1.f + __expf(-fabsf(x))) - 0.693147180559945f;
}

// Pack W1 [300,128] -> f16 B-frag layout [10kk][8nt][64l][8j] at ws[0..40960)
// and W2 [128,128] -> [4kk][8nt][64l][8j] at ws[40960..57344).
__global__ void prep_pack(const float* __restrict__ W1, const float* __restrict__ W2,
                          unsigned short* __restrict__ ws) {
  int gid = blockIdx.x * 256 + threadIdx.x;
  if (gid < 40960) {
    int j = gid & 7, l = (gid >> 3) & 63, ntg = (gid >> 9) & 7, kk = gid >> 12;
    int k = kk * 32 + (l >> 4) * 8 + j;
    int h = ntg * 16 + (l & 15);
    float v = (k < 300) ? W1[k * 128 + h] : 0.f;
    ws[gid] = __builtin_bit_cast(unsigned short, (_Float16)v);
  } else if (gid < 57344) {
    int g2 = gid - 40960;
    int j = g2 & 7, l = (g2 >> 3) & 63, ntg = (g2 >> 9) & 7, kk = g2 >> 12;
    int k = kk * 32 + (l >> 4) * 8 + j;
    int h = ntg * 16 + (l & 15);
    ws[gid] = __builtin_bit_cast(unsigned short, (_Float16)W2[k * 128 + h]);
  }
}

__global__ __launch_bounds__(512, 1) void interaction_kernel(
    const float* __restrict__ nodef, const float* __restrict__ pos,
    const float* __restrict__ valid, const unsigned short* __restrict__ ws,
    const float* __restrict__ Wa1, const float* __restrict__ Wa2,
    const float* __restrict__ Wa3, float* __restrict__ out) {
  __shared__ __align__(16) unsigned short W1pk[40960];  // 81,920 B
  __shared__ __align__(16) unsigned short W2pk[16384];  // 32,768 B
  __shared__ __align__(16) _Float16 ytile[64 * 136];    // 17,408 B (reused as f32 red)
  __shared__ float d_lds[256];
  __shared__ int k0arr[256];
  __shared__ unsigned short jord[256];
  __shared__ int kklo[16], kkhi[16];
  __shared__ float xrow[128], h1row[128], hhrow[128], a2row[128];
  __shared__ float partial[4][128];

  const int t = threadIdx.x;
  const int bid = blockIdx.x;  // b*256 + i
  const int b = bid >> 8;

  // ---- stage packed weights into LDS (16B coalesced) ----
  {
    const uint4* src = (const uint4*)ws;
    uint4* d1 = (uint4*)W1pk;
    for (int i = t; i < 5120; i += 512) d1[i] = src[i];
    uint4* d2 = (uint4*)W2pk;
    for (int i = t; i < 2048; i += 512) d2[i] = src[5120 + i];
  }
  if (t < 128) xrow[t] = nodef[bid * 128 + t];
  if (t < 256) {
    const float qx = pos[bid * 3 + 0], qy = pos[bid * 3 + 1], qz = pos[bid * 3 + 2];
    const float px = pos[(b * 256 + t) * 3 + 0];
    const float py = pos[(b * 256 + t) * 3 + 1];
    const float pz = pos[(b * 256 + t) * 3 + 2];
    const float dx = px - qx, dy = py - qy, dz = pz - qz;
    const float dd = sqrtf(dx * dx + dy * dy + dz * dz);
    d_lds[t] = dd;
    k0arr[t] = __float2int_rn(dd * 10.f);
  }
  __syncthreads();

  // ---- stable rank-sort of j by window center (deterministic) ----
  if (t < 256) {
    const int key = k0arr[t];
    int rank = 0;
    for (int j2 = 0; j2 < 256; ++j2) {
      const int k2 = k0arr[j2];
      rank += (k2 < key || (k2 == key && j2 < t)) ? 1 : 0;
    }
    jord[rank] = (unsigned short)t;
  }
  // h1 = x @ Wa1 (partials over 4 thread-groups)
  {
    const int hh_ = t & 127, part = t >> 7;
    float a = 0.f;
#pragma unroll 8
    for (int k = part * 32; k < part * 32 + 32; ++k) a += xrow[k] * Wa1[k * 128 + hh_];
    partial[part][hh_] = a;
  }
  __syncthreads();
  // per sorted-16-group K-step ranges
  if (t < 16) {
    const int base = t * 16;
    const int klo = max(0, k0arr[jord[base]] - 16);
    const int khi = min(319, k0arr[jord[base + 15]] + 16);
    kklo[t] = klo >> 5;
    kkhi[t] = (khi >> 5) + 1;
  }
  if (t < 128)
    h1row[t] = partial[0][t] + partial[1][t] + partial[2][t] + partial[3][t];
  __syncthreads();

  const int wid = t >> 6, l = t & 63;
  const int jg = wid >> 1, hgrp = wid & 1;  // wave tile: 16 j-rows x 64 h-cols
  const int lr = l & 15, lq = l >> 4;
  float sumv[4] = {0.f, 0.f, 0.f, 0.f};

  // ---- main loop: 4 chunks of 64 sorted j's ----
  for (int cc = 0; cc < 4; ++cc) {
    const int g = cc * 4 + jg;
    const float dd = d_lds[jord[cc * 64 + jg * 16 + lr]];
    const int lo = kklo[g], hi = kkhi[g];

    // GEMM1: acc[nt] (16j x 16h tiles), K-steps restricted to group window
    f32x4 acc[4] = {f32x4{0,0,0,0}, f32x4{0,0,0,0}, f32x4{0,0,0,0}, f32x4{0,0,0,0}};
    for (int kk = lo; kk < hi; ++kk) {
      f16x8 afr;
      const float kbase = (float)(kk * 32 + lq * 8);
#pragma unroll
      for (int j = 0; j < 8; ++j) {
        const float df = dd - 0.1f * (kbase + (float)j);
        afr[j] = (_Float16)__expf(-10.f * df * df);  // underflows to 0 outside window
      }
#pragma unroll
      for (int nt = 0; nt < 4; ++nt) {
        const f16x8 bfr = *(const f16x8*)&W1pk[((kk * 8 + hgrp * 4 + nt) * 64 + l) * 8];
        acc[nt] = __builtin_amdgcn_mfma_f32_16x16x32_f16(afr, bfr, acc[nt], 0, 0, 0);
      }
    }
    // ssp -> y tile (f16)
#pragma unroll
    for (int nt = 0; nt < 4; ++nt)
#pragma unroll
      for (int r = 0; r < 4; ++r)
        ytile[(jg * 16 + lq * 4 + r) * 136 + hgrp * 64 + nt * 16 + lr] =
            (_Float16)sspf(acc[nt][r]);
    __syncthreads();

    // GEMM2: z = y @ W2 (dense K=128)
    f32x4 acc2[4] = {f32x4{0,0,0,0}, f32x4{0,0,0,0}, f32x4{0,0,0,0}, f32x4{0,0,0,0}};
#pragma unroll
    for (int kk = 0; kk < 4; ++kk) {
      const f16x8 afr = *(const f16x8*)&ytile[(jg * 16 + lr) * 136 + kk * 32 + lq * 8];
#pragma unroll
      for (int nt = 0; nt < 4; ++nt) {
        const f16x8 bfr = *(const f16x8*)&W2pk[((kk * 8 + hgrp * 4 + nt) * 64 + l) * 8];
        acc2[nt] = __builtin_amdgcn_mfma_f32_16x16x32_f16(afr, bfr, acc2[nt], 0, 0, 0);
      }
    }
#pragma unroll
    for (int nt = 0; nt < 4; ++nt)
#pragma unroll
      for (int r = 0; r < 4; ++r) sumv[nt] += sspf(acc2[nt][r]);
    __syncthreads();  // ytile safe to overwrite next chunk
  }

  // ---- reduce sum_j partials (16 per h-column) via f32 scratch over ytile ----
  {
    float* red = (float*)ytile;
#pragma unroll
    for (int nt = 0; nt < 4; ++nt)
      red[(jg * 4 + lq) * 128 + hgrp * 64 + nt * 16 + lr] = sumv[nt];
  }
  __syncthreads();
  if (t < 128) {
    const float* red = (const float*)ytile;
    float s = 0.f;
#pragma unroll
    for (int q = 0; q < 16; ++q) s += red[q * 128 + t];
    hhrow[t] = h1row[t] * s;  // CFConv: h * sum_j filt
  }
  __syncthreads();
  // a2 = ssp(hh @ Wa2)
  {
    const int hh_ = t & 127, part = t >> 7;
    float a = 0.f;
#pragma unroll 8
    for (int k = part * 32; k < part * 32 + 32; ++k) a += hhrow[k] * Wa2[k * 128 + hh_];
    partial[part][hh_] = a;
  }
  __syncthreads();
  if (t < 128)
    a2row[t] = sspf(partial[0][t] + partial[1][t] + partial[2][t] + partial[3][t]);
  __syncthreads();
  // out = x + (a2 @ Wa3) * valid
  {
    const int hh_ = t & 127, part = t >> 7;
    float a = 0.f;
#pragma unroll 8
    for (int k = part * 32; k < part * 32 + 32; ++k) a += a2row[k] * Wa3[k * 128 + hh_];
    partial[part][hh_] = a;
  }
  __syncthreads();
  if (t < 128)
    out[bid * 128 + t] =
        xrow[t] + (partial[0][t] + partial[1][t] + partial[2][t] + partial[3][t]) * valid[bid];
}

extern "C" void kernel_launch(void* const* d_in, const int* in_sizes, int n_in,
                              void* d_out, int out_size, void* d_ws, size_t ws_size,
                              hipStream_t stream) {
  const float* nodef = (const float*)d_in[0];
  const float* pos   = (const float*)d_in[1];
  const float* valid = (const float*)d_in[2];
  const float* W1    = (const float*)d_in[3];
  const float* W2    = (const float*)d_in[4];
  const float* Wa1   = (const float*)d_in[5];
  const float* Wa2   = (const float*)d_in[6];
  const float* Wa3   = (const float*)d_in[7];
  float* outp = (float*)d_out;
  unsigned short* wsp = (unsigned short*)d_ws;  // 57,344 f16 = 114,688 B

  prep_pack<<<224, 256, 0, stream>>>(W1, W2, wsp);
  interaction_kernel<<<1024, 512, 0, stream>>>(nodef, pos, valid, wsp,
                                               Wa1, Wa2, Wa3, outp);
}

// Round 3
// 61.524 us; speedup vs baseline: 3.5839x; 1.8347x over previous
//
#include <hip/hip_runtime.h>

// InteractionLayer (SchNet-style) — MFMA f16, occupancy-optimized. MI355X gfx950.
// Shapes hardcoded: B=4, N=256, NF=H=128, K=300 filters, gamma=10, spacing=0.1.
// Block = one (b,i) row: 1024 blocks x 512 threads (8 waves: jg 0..3 x hgrp 0..1),
// ~57 KB LDS -> 2 blocks/CU (16 waves) for barrier-gap overlap.
// GEMM1: rbf[64j x 320k] @ W1[320x128] via 16x16x32 f16 MFMA. rbf A-fragments are
//   computed in registers with an exact exp-recurrence (2 transcendentals per 8
//   elems); K-steps restricted per sorted 16-row group (window +-12).
//   W1 B-fragments are read DIRECTLY FROM GLOBAL (pre-packed, L2-resident 80 KB,
//   coalesced 16B/lane) instead of LDS -> frees 82 KB LDS.
// GEMM2: ssp(y)[64x128] @ W2[128x128] dense MFMA, W2 fragments in LDS.
//
// MFMA 16x16x32 layouts (gfx950):
//   A: lane l elem j -> A[l&15][(l>>4)*8 + j]
//   B: lane l elem j -> B[(l>>4)*8 + j][l&15]
//   D: lane l reg  r -> D[(l>>4)*4 + r][l&15]

typedef _Float16 f16x8 __attribute__((ext_vector_type(8)));
typedef float f32x4 __attribute__((ext_vector_type(4)));

__device__ __forceinline__ float exp2f_fast(float x) {
#if __has_builtin(__builtin_amdgcn_exp2f)
  return __builtin_amdgcn_exp2f(x);
#else
  return __exp2f(x);
#endif
}
__device__ __forceinline__ float log2f_fast(float x) {
#if __has_builtin(__builtin_amdgcn_logf)
  return __builtin_amdgcn_logf(x);
#else
  return __log2f(x);
#endif
}

// ssp(x) = softplus(x) + log(0.5) = max(x,0) - ln2 + ln2*log2(1 + 2^(-|x|*log2e))
__device__ __forceinline__ float sspf(float x) {
  const float e = exp2f_fast(-1.44269504f * fabsf(x));
  const float l = log2f_fast(1.f + e);
  return fmaf(0.69314718f, l, fmaxf(x, 0.f) - 0.69314718f);
}

// Pack W1 [300,128] -> f16 B-frag layout [10kk][8nt][64l][8j] at ws[0..40960)
// and W2 [128,128] -> [4kk][8nt][64l][8j] at ws[40960..57344).
__global__ void prep_pack(const float* __restrict__ W1, const float* __restrict__ W2,
                          unsigned short* __restrict__ ws) {
  int gid = blockIdx.x * 256 + threadIdx.x;
  if (gid < 40960) {
    int j = gid & 7, l = (gid >> 3) & 63, ntg = (gid >> 9) & 7, kk = gid >> 12;
    int k = kk * 32 + (l >> 4) * 8 + j;
    int h = ntg * 16 + (l & 15);
    float v = (k < 300) ? W1[k * 128 + h] : 0.f;
    ws[gid] = __builtin_bit_cast(unsigned short, (_Float16)v);
  } else if (gid < 57344) {
    int g2 = gid - 40960;
    int j = g2 & 7, l = (g2 >> 3) & 63, ntg = (g2 >> 9) & 7, kk = g2 >> 12;
    int k = kk * 32 + (l >> 4) * 8 + j;
    int h = ntg * 16 + (l & 15);
    ws[gid] = __builtin_bit_cast(unsigned short, (_Float16)W2[k * 128 + h]);
  }
}

__global__ __launch_bounds__(512, 4) void interaction_kernel(
    const float* __restrict__ nodef, const float* __restrict__ pos,
    const float* __restrict__ valid, const unsigned short* __restrict__ ws,
    const float* __restrict__ Wa1, const float* __restrict__ Wa2,
    const float* __restrict__ Wa3, float* __restrict__ out) {
  __shared__ __align__(16) unsigned short W2pk[16384];  // 32,768 B
  __shared__ __align__(16) _Float16 ytile[64 * 136];    // 17,408 B (reused as f32 red)
  __shared__ float d_lds[256];
  __shared__ int k0arr[256];
  __shared__ unsigned short jord[256];
  __shared__ int kklo[16], kkhi[16];
  __shared__ float xrow[128], h1row[128], hhrow[128], a2row[128];
  __shared__ float partial[4][128];

  const int t = threadIdx.x;
  const int bid = blockIdx.x;  // b*256 + i
  const int b = bid >> 8;

  // ---- stage W2 fragments into LDS (16B coalesced) ----
  {
    const uint4* src = (const uint4*)ws;
    uint4* d2 = (uint4*)W2pk;
    for (int i = t; i < 2048; i += 512) d2[i] = src[5120 + i];
  }
  if (t < 128) xrow[t] = nodef[bid * 128 + t];
  if (t < 256) {
    const float qx = pos[bid * 3 + 0], qy = pos[bid * 3 + 1], qz = pos[bid * 3 + 2];
    const float px = pos[(b * 256 + t) * 3 + 0];
    const float py = pos[(b * 256 + t) * 3 + 1];
    const float pz = pos[(b * 256 + t) * 3 + 2];
    const float dx = px - qx, dy = py - qy, dz = pz - qz;
    const float dd = sqrtf(dx * dx + dy * dy + dz * dz);
    d_lds[t] = dd;
    k0arr[t] = __float2int_rn(dd * 10.f);
  }
  __syncthreads();

  // ---- stable rank-sort of j by window center (deterministic) ----
  if (t < 256) {
    const int key = k0arr[t];
    int rank = 0;
    for (int j2 = 0; j2 < 256; ++j2) {
      const int k2 = k0arr[j2];
      rank += (k2 < key || (k2 == key && j2 < t)) ? 1 : 0;
    }
    jord[rank] = (unsigned short)t;
  }
  // h1 = x @ Wa1 (partials over 4 thread-groups)
  {
    const int hh_ = t & 127, part = t >> 7;
    float a = 0.f;
#pragma unroll 8
    for (int k = part * 32; k < part * 32 + 32; ++k) a += xrow[k] * Wa1[k * 128 + hh_];
    partial[part][hh_] = a;
  }
  __syncthreads();
  // per sorted-16-group K-step ranges (window +-12: exp(-10*1.2^2)=5.6e-7)
  if (t < 16) {
    const int base = t * 16;
    const int klo = max(0, k0arr[jord[base]] - 12);
    const int khi = min(319, k0arr[jord[base + 15]] + 12);
    kklo[t] = klo >> 5;
    kkhi[t] = (khi >> 5) + 1;
  }
  if (t < 128)
    h1row[t] = partial[0][t] + partial[1][t] + partial[2][t] + partial[3][t];
  __syncthreads();

  const int wid = t >> 6, l = t & 63;
  const int jg = wid >> 1, hgrp = wid & 1;  // wave tile: 16 j-rows x 64 h-cols
  const int lr = l & 15, lq = l >> 4;
  float sumv[4] = {0.f, 0.f, 0.f, 0.f};

  // ---- main loop: 4 chunks of 64 sorted j's ----
  for (int cc = 0; cc < 4; ++cc) {
    const int g = cc * 4 + jg;
    const float dd = d_lds[jord[cc * 64 + jg * 16 + lr]];
    const int lo = kklo[g], hi = kkhi[g];

    // GEMM1: acc[nt] (16j x 16h tiles), K-steps restricted to group window.
    f32x4 acc[4] = {f32x4{0,0,0,0}, f32x4{0,0,0,0}, f32x4{0,0,0,0}, f32x4{0,0,0,0}};
    for (int kk = lo; kk < hi; ++kk) {
      // rbf via exact exp recurrence: a_j = -10*(x0-0.1j)^2,
      // a_{j+1}-a_j = 2*x0-0.2j-0.1 -> v *= r, r *= e^-0.2.
      // Underflow-safe: if e^{a_0} underflows, every later true value in the
      // 8-run is <= e^-43 (negligible vs threshold), so 0 is correct enough.
      const float x0 = dd - 0.1f * (float)(kk * 32 + lq * 8);
      float v = exp2f_fast(-14.4269504f * x0 * x0);           // e^{a_0}
      float r = exp2f_fast(fmaf(2.88539008f, x0, -0.144269504f));  // e^{2x0-0.1}
      f16x8 afr;
      afr[0] = (_Float16)v;
#pragma unroll
      for (int j = 1; j < 8; ++j) {
        v *= r;
        r *= 0.818730753f;  // e^-0.2
        afr[j] = (_Float16)v;
      }
      // B-fragments straight from global (L2-resident packed W1)
#pragma unroll
      for (int nt = 0; nt < 4; ++nt) {
        const f16x8 bfr = *(const f16x8*)&ws[((kk * 8 + hgrp * 4 + nt) * 64 + l) * 8];
        acc[nt] = __builtin_amdgcn_mfma_f32_16x16x32_f16(afr, bfr, acc[nt], 0, 0, 0);
      }
    }
    // ssp -> y tile (f16)
#pragma unroll
    for (int nt = 0; nt < 4; ++nt)
#pragma unroll
      for (int r = 0; r < 4; ++r)
        ytile[(jg * 16 + lq * 4 + r) * 136 + hgrp * 64 + nt * 16 + lr] =
            (_Float16)sspf(acc[nt][r]);
    __syncthreads();

    // GEMM2: z = y @ W2 (dense K=128)
    f32x4 acc2[4] = {f32x4{0,0,0,0}, f32x4{0,0,0,0}, f32x4{0,0,0,0}, f32x4{0,0,0,0}};
#pragma unroll
    for (int kk = 0; kk < 4; ++kk) {
      const f16x8 afr = *(const f16x8*)&ytile[(jg * 16 + lr) * 136 + kk * 32 + lq * 8];
#pragma unroll
      for (int nt = 0; nt < 4; ++nt) {
        const f16x8 bfr = *(const f16x8*)&W2pk[((kk * 8 + hgrp * 4 + nt) * 64 + l) * 8];
        acc2[nt] = __builtin_amdgcn_mfma_f32_16x16x32_f16(afr, bfr, acc2[nt], 0, 0, 0);
      }
    }
#pragma unroll
    for (int nt = 0; nt < 4; ++nt)
#pragma unroll
      for (int r = 0; r < 4; ++r) sumv[nt] += sspf(acc2[nt][r]);
    __syncthreads();  // ytile safe to overwrite next chunk
  }

  // ---- reduce sum_j partials (16 per h-column) via f32 scratch over ytile ----
  {
    float* red = (float*)ytile;
#pragma unroll
    for (int nt = 0; nt < 4; ++nt)
      red[(jg * 4 + lq) * 128 + hgrp * 64 + nt * 16 + lr] = sumv[nt];
  }
  __syncthreads();
  if (t < 128) {
    const float* red = (const float*)ytile;
    float s = 0.f;
#pragma unroll
    for (int q = 0; q < 16; ++q) s += red[q * 128 + t];
    hhrow[t] = h1row[t] * s;  // CFConv: h * sum_j filt
  }
  __syncthreads();
  // a2 = ssp(hh @ Wa2)
  {
    const int hh_ = t & 127, part = t >> 7;
    float a = 0.f;
#pragma unroll 8
    for (int k = part * 32; k < part * 32 + 32; ++k) a += hhrow[k] * Wa2[k * 128 + hh_];
    partial[part][hh_] = a;
  }
  __syncthreads();
  if (t < 128)
    a2row[t] = sspf(partial[0][t] + partial[1][t] + partial[2][t] + partial[3][t]);
  __syncthreads();
  // out = x + (a2 @ Wa3) * valid
  {
    const int hh_ = t & 127, part = t >> 7;
    float a = 0.f;
#pragma unroll 8
    for (int k = part * 32; k < part * 32 + 32; ++k) a += a2row[k] * Wa3[k * 128 + hh_];
    partial[part][hh_] = a;
  }
  __syncthreads();
  if (t < 128)
    out[bid * 128 + t] =
        xrow[t] + (partial[0][t] + partial[1][t] + partial[2][t] + partial[3][t]) * valid[bid];
}

extern "C" void kernel_launch(void* const* d_in, const int* in_sizes, int n_in,
                              void* d_out, int out_size, void* d_ws, size_t ws_size,
                              hipStream_t stream) {
  const float* nodef = (const float*)d_in[0];
  const float* pos   = (const float*)d_in[1];
  const float* valid = (const float*)d_in[2];
  const float* W1    = (const float*)d_in[3];
  const float* W2    = (const float*)d_in[4];
  const float* Wa1   = (const float*)d_in[5];
  const float* Wa2   = (const float*)d_in[6];
  const float* Wa3   = (const float*)d_in[7];
  float* outp = (float*)d_out;
  unsigned short* wsp = (unsigned short*)d_ws;  // 57,344 f16 = 114,688 B

  prep_pack<<<224, 256, 0, stream>>>(W1, W2, wsp);
  interaction_kernel<<<1024, 512, 0, stream>>>(nodef, pos, valid, wsp,
                                               Wa1, Wa2, Wa3, outp);
}